// Round 10
// baseline (241.948 us; speedup 1.0000x reference)
//
#include <hip/hip_runtime.h>
#include <hip/hip_bf16.h>
#include <math.h>

// Problem shape (SimpleGCN):
//   node_features [N=100000, 128] f32
//   edge_index    [2, E=1200000] i32   (row 0 = src, row 1 = dst)
//   post_mask     [P=50000] i32
// out[p] = sigmoid( relu( (emb + segsum(emb[src]->dst))[post[p]] @ Wc + bc ) @ Wo + bo )
//
// Round-10: round-9's cooperative mega-kernel never launched (unchecked API
// failure -> zero output). Same overlap idea WITHOUT the cooperative API:
// k_build = one regular kernel whose blocks split into [encode-MFMA] ||
// [CSR chain with subset spin-barriers]. Deadlock-free by construction:
// waiting (CSR) blocks are dispatched last; encode blocks never wait and
// retire, freeing slots. Gather/head/out remain the proven round-8 kernels
// at full occupancy. 5 dispatches total (was 10).

#define HIDDEN 64
#define NODE_DIM 128
#define SCAN_CHUNK 1024

typedef __attribute__((ext_vector_type(8))) short short8;   // 8 bf16 (4 VGPR)
typedef __attribute__((ext_vector_type(4))) float floatx4;  // mfma C/D frag

union F2B { short8 s; __hip_bfloat162 h[4]; };

__device__ inline short8 cvt8(const float4& p, const float4& q) {
    F2B u;
    u.h[0] = __float22bfloat162_rn(make_float2(p.x, p.y));
    u.h[1] = __float22bfloat162_rn(make_float2(p.z, p.w));
    u.h[2] = __float22bfloat162_rn(make_float2(q.x, q.y));
    u.h[3] = __float22bfloat162_rn(make_float2(q.z, q.w));
    return u.s;
}

// hi/lo bf16 split of 8 floats: hi = bf16(x), lo = bf16(x - float(hi)).
__device__ inline void cvt8_split(const float4& p, const float4& q,
                                  short8& hi, short8& lo) {
    const float f[8] = {p.x, p.y, p.z, p.w, q.x, q.y, q.z, q.w};
    F2B uh, ul;
    #pragma unroll
    for (int jj = 0; jj < 4; ++jj) {
        const float2 v = make_float2(f[2 * jj], f[2 * jj + 1]);
        const __hip_bfloat162 h = __float22bfloat162_rn(v);
        const float2 hv = __bfloat1622float2(h);
        ul.h[jj] = __float22bfloat162_rn(make_float2(v.x - hv.x, v.y - hv.y));
        uh.h[jj] = h;
    }
    hi = uh.s; lo = ul.s;
}

// Subset spin-barrier for the CSR blocks (agent-scope fences for cross-XCD).
__device__ inline void cbar(int* ctr, int target) {
    __syncthreads();
    if (threadIdx.x == 0) {
        __builtin_amdgcn_fence(__ATOMIC_RELEASE, "agent");
        __hip_atomic_fetch_add(ctr, 1, __ATOMIC_RELAXED, __HIP_MEMORY_SCOPE_AGENT);
        while (__hip_atomic_load(ctr, __ATOMIC_RELAXED, __HIP_MEMORY_SCOPE_AGENT) < target)
            __builtin_amdgcn_s_sleep(8);
        __builtin_amdgcn_fence(__ATOMIC_ACQUIRE, "agent");
    }
    __syncthreads();
}

struct BuildP {
    const float* A; const int* srcs; const int* dsts; const int* post;
    const float* We; const float* be;
    __hip_bfloat16* emb16;
    int* slots; int* count; int* listCnt;
    unsigned int* partials; unsigned int* bits;
    int* row_start; int* nodelist; int* inv; int* bars;
    int n_nodes, n_edges, n_posts, n_tiles, eblk, cblk;
};

// ---------------------------------------------------------------------------
// k_build: blocks [0,eblk) = MFMA encode; blocks [eblk,grid) = CSR chain
// (setflags -> count -> scan(lookback) -> fill) with subset barriers.
// ---------------------------------------------------------------------------
__global__ __launch_bounds__(256, 2) void k_build(BuildP P)
{
    const int tid  = threadIdx.x;
    const int lane = tid & 63;
    const int r    = lane & 15;
    const int quad = lane >> 4;

    if ((int)blockIdx.x < P.eblk) {
        // ---- MFMA encode: emb16 = bf16(relu(A @ We + be)) ----
        short8 Wb[4][4];
        #pragma unroll
        for (int ks = 0; ks < 4; ++ks)
            #pragma unroll
            for (int nt = 0; nt < 4; ++nt) {
                F2B u;
                #pragma unroll
                for (int jj = 0; jj < 4; ++jj) {
                    const int k0 = ks * 32 + quad * 8 + 2 * jj;
                    const float lo = P.We[(size_t)k0 * HIDDEN + nt * 16 + r];
                    const float hi = P.We[(size_t)(k0 + 1) * HIDDEN + nt * 16 + r];
                    u.h[jj] = __float22bfloat162_rn(make_float2(lo, hi));
                }
                Wb[ks][nt] = u.s;
            }
        float bias[4];
        #pragma unroll
        for (int nt = 0; nt < 4; ++nt) bias[nt] = P.be[nt * 16 + r];

        const int widE = blockIdx.x * 4 + (tid >> 6);
        const int nwE  = P.eblk * 4;
        for (int t = widE; t < P.n_tiles; t += nwE) {
            const float* Arow = P.A + (size_t)t * 16 * NODE_DIM + (size_t)r * NODE_DIM + quad * 8;
            float4 a[4][2];
            #pragma unroll
            for (int ks = 0; ks < 4; ++ks) {
                a[ks][0] = *(const float4*)(Arow + ks * 32);
                a[ks][1] = *(const float4*)(Arow + ks * 32 + 4);
            }
            floatx4 acc[4] = {};
            #pragma unroll
            for (int ks = 0; ks < 4; ++ks) {
                const short8 af = cvt8(a[ks][0], a[ks][1]);
                #pragma unroll
                for (int nt = 0; nt < 4; ++nt)
                    acc[nt] = __builtin_amdgcn_mfma_f32_16x16x32_bf16(af, Wb[ks][nt], acc[nt], 0, 0, 0);
            }
            #pragma unroll
            for (int nt = 0; nt < 4; ++nt)
                #pragma unroll
                for (int g = 0; g < 4; ++g) {
                    const int node = t * 16 + quad * 4 + g;
                    const float h = fmaxf(acc[nt][g] + bias[nt], 0.0f);
                    P.emb16[(size_t)node * HIDDEN + nt * 16 + r] = __float2bfloat16(h);
                }
        }
        // tail nodes (n_nodes % 16) — 0 for this shape
        const int rem = P.n_nodes - P.n_tiles * 16;
        if (rem > 0 && widE == 0) {
            for (int n = P.n_tiles * 16; n < P.n_nodes; ++n) {
                float acc = P.be[lane];
                const float* row = P.A + (size_t)n * NODE_DIM;
                for (int k = 0; k < NODE_DIM; ++k)
                    acc = fmaf(row[k], P.We[(size_t)k * HIDDEN + lane], acc);
                P.emb16[(size_t)n * HIDDEN + lane] = __float2bfloat16(fmaxf(acc, 0.0f));
            }
        }
    } else {
        // ---- CSR chain ----
        const int cb    = blockIdx.x - P.eblk;
        const int ctid  = cb * 256 + tid;
        const int cstep = P.cblk * 256;

        // setflags: dedup via atomicOr return; compact list + inverse map
        for (int p = ctid; p < P.n_posts; p += cstep) {
            const int n = P.post[p];
            const unsigned int bit = 1u << (n & 31);
            const unsigned int old = atomicOr(&P.bits[n >> 5], bit);
            if (!(old & bit)) {
                const int i = atomicAdd(P.listCnt, 1);
                P.nodelist[i] = n;
                P.inv[n] = i;
            }
        }
        cbar(P.bars + 0, P.cblk);

        // count in-degree of flagged destinations (bits = L1-resident)
        for (int e = ctid; e < P.n_edges; e += cstep) {
            const int d = P.dsts[e];
            if ((P.bits[d >> 5] >> (d & 31)) & 1u) atomicAdd(&P.count[d], 1);
        }
        cbar(P.bars + 1, P.cblk);

        // exclusive scan with decoupled lookback (1024-wide chunks)
        {
            __shared__ int s[256];
            __shared__ int sExc;
            const int nb = (P.n_nodes + SCAN_CHUNK - 1) / SCAN_CHUNK;   // 98
            if (cb < nb) {
                const int base = cb * SCAN_CHUNK + tid * 4;
                const int n = P.n_nodes;
                int c0 = (base + 0 < n) ? P.count[base + 0] : 0;
                int c1 = (base + 1 < n) ? P.count[base + 1] : 0;
                int c2 = (base + 2 < n) ? P.count[base + 2] : 0;
                int c3 = (base + 3 < n) ? P.count[base + 3] : 0;
                const int t4 = c0 + c1 + c2 + c3;
                s[tid] = t4;
                __syncthreads();
                #pragma unroll
                for (int off = 1; off < 256; off <<= 1) {
                    int v = (tid >= off) ? s[tid - off] : 0;
                    __syncthreads();
                    s[tid] += v;
                    __syncthreads();
                }
                if (tid == 0) {
                    const unsigned int total = (unsigned int)s[255];
                    if (cb == 0) {
                        __hip_atomic_store(&P.partials[0], (2u << 30) | total,
                                           __ATOMIC_RELEASE, __HIP_MEMORY_SCOPE_AGENT);
                        sExc = 0;
                    } else {
                        __hip_atomic_store(&P.partials[cb], (1u << 30) | total,
                                           __ATOMIC_RELEASE, __HIP_MEMORY_SCOPE_AGENT);
                        int exc = 0, j = cb - 1;
                        while (true) {
                            const unsigned int v = __hip_atomic_load(&P.partials[j],
                                __ATOMIC_ACQUIRE, __HIP_MEMORY_SCOPE_AGENT);
                            const unsigned int st = v >> 30;
                            if (st == 0u) { __builtin_amdgcn_s_sleep(1); continue; }
                            exc += (int)(v & 0x3FFFFFFFu);
                            if (st == 2u) break;
                            --j;
                        }
                        __hip_atomic_store(&P.partials[cb], (2u << 30) | (unsigned int)(exc + (int)total),
                                           __ATOMIC_RELEASE, __HIP_MEMORY_SCOPE_AGENT);
                        sExc = exc;
                    }
                }
                __syncthreads();
                int run = sExc + s[tid] - t4;
                if (base + 0 < n) P.row_start[base + 0] = run;   run += c0;
                if (base + 1 < n) P.row_start[base + 1] = run;   run += c1;
                if (base + 2 < n) P.row_start[base + 2] = run;   run += c2;
                if (base + 3 < n) P.row_start[base + 3] = run;
            }
        }
        cbar(P.bars + 2, P.cblk);

        // fill slot lists (row_start becomes row_end)
        for (int e = ctid; e < P.n_edges; e += cstep) {
            const int d = P.dsts[e];
            if (!((P.bits[d >> 5] >> (d & 31)) & 1u)) continue;
            const int idx = atomicAdd(&P.row_start[d], 1);
            P.slots[idx] = P.srcs[e];
        }
    }
}

// ---------------------------------------------------------------------------
// Gather (proven round-8): one wave per compact node. 8 groups x 8 lanes;
// one 128 B bf16 row per group; 2-deep unroll -> 16 rows in flight.
// ---------------------------------------------------------------------------
__global__ __launch_bounds__(256) void k_gather(
    const int* __restrict__ nodelist, const int* __restrict__ listCnt,
    const int* __restrict__ row_end, const int* __restrict__ count,
    const int* __restrict__ slots, const __hip_bfloat16* __restrict__ emb16,
    float* __restrict__ msg_c)
{
    const int lane = threadIdx.x & 63;
    const int j    = lane & 7;
    const int g    = lane >> 3;
    const int gw   = (blockIdx.x * 256 + threadIdx.x) >> 6;
    const int nw   = gridDim.x * 4;
    const int nc   = listCnt[0];

    for (int i = gw; i < nc; i += nw) {
        const int n    = nodelist[i];
        const int m    = count[n];
        const int base = row_end[n] - m;

        float2 a0 = {0.f, 0.f}, a1 = {0.f, 0.f}, a2 = {0.f, 0.f}, a3 = {0.f, 0.f};
        #define ACC8(v)  do { F2B u; u.s = (v); float2 t;                       \
            t = __bfloat1622float2(u.h[0]); a0.x += t.x; a0.y += t.y;           \
            t = __bfloat1622float2(u.h[1]); a1.x += t.x; a1.y += t.y;           \
            t = __bfloat1622float2(u.h[2]); a2.x += t.x; a2.y += t.y;           \
            t = __bfloat1622float2(u.h[3]); a3.x += t.x; a3.y += t.y; } while (0)

        if (g == 0) {
            const short8 v = *(const short8*)(emb16 + (size_t)n * HIDDEN + j * 8);
            ACC8(v);
        }
        int c = g;
        for (; c + 8 < m; c += 16) {
            const int s0 = slots[base + c];
            const int s1 = slots[base + c + 8];
            const short8 v0 = *(const short8*)(emb16 + (size_t)s0 * HIDDEN + j * 8);
            const short8 v1 = *(const short8*)(emb16 + (size_t)s1 * HIDDEN + j * 8);
            ACC8(v0); ACC8(v1);
        }
        for (; c < m; c += 8) {
            const int s0 = slots[base + c];
            const short8 v0 = *(const short8*)(emb16 + (size_t)s0 * HIDDEN + j * 8);
            ACC8(v0);
        }
        #undef ACC8

        #pragma unroll
        for (int off = 8; off < 64; off <<= 1) {
            a0.x += __shfl_xor(a0.x, off); a0.y += __shfl_xor(a0.y, off);
            a1.x += __shfl_xor(a1.x, off); a1.y += __shfl_xor(a1.y, off);
            a2.x += __shfl_xor(a2.x, off); a2.y += __shfl_xor(a2.y, off);
            a3.x += __shfl_xor(a3.x, off); a3.y += __shfl_xor(a3.y, off);
        }
        if (g == 0) {
            float4* dst = (float4*)(msg_c + (size_t)i * HIDDEN + j * 8);
            dst[0] = make_float4(a0.x, a0.y, a1.x, a1.y);
            dst[1] = make_float4(a2.x, a2.y, a3.x, a3.y);
        }
    }
}

// ---------------------------------------------------------------------------
// Head (MFMA, proven round-8): wave per 16 compact rows of msg_c.
// ---------------------------------------------------------------------------
__global__ __launch_bounds__(256) void k_head_mfma(
    const int* __restrict__ listCnt, const float* __restrict__ msg_c,
    const float* __restrict__ Wc, const float* __restrict__ bc,
    const float* __restrict__ Wo, const float* __restrict__ bo,
    float* __restrict__ res_c)
{
    const int lane = threadIdx.x & 63;
    const int r    = lane & 15;
    const int quad = lane >> 4;

    short8 Wb[2][4];
    #pragma unroll
    for (int ks = 0; ks < 2; ++ks)
        #pragma unroll
        for (int nt = 0; nt < 4; ++nt) {
            F2B u;
            #pragma unroll
            for (int jj = 0; jj < 4; ++jj) {
                const int k0 = ks * 32 + quad * 8 + 2 * jj;
                const float lo = Wc[(size_t)k0 * HIDDEN + nt * 16 + r];
                const float hi = Wc[(size_t)(k0 + 1) * HIDDEN + nt * 16 + r];
                u.h[jj] = __float22bfloat162_rn(make_float2(lo, hi));
            }
            Wb[ks][nt] = u.s;
        }
    float bias[4], wo[4];
    #pragma unroll
    for (int nt = 0; nt < 4; ++nt) { bias[nt] = bc[nt * 16 + r]; wo[nt] = Wo[nt * 16 + r]; }
    const float bo_s = bo[0];

    const int nc      = listCnt[0];
    const int n_tiles = (nc + 15) / 16;
    const int wid     = (blockIdx.x * 256 + threadIdx.x) >> 6;
    const int nwaves  = gridDim.x * 4;

    for (int tile = wid; tile < n_tiles; tile += nwaves) {
        const int i0  = tile * 16;
        const int row = i0 + r;
        floatx4 acc[4] = {};
        #pragma unroll
        for (int ks = 0; ks < 2; ++ks) {
            float4 f0 = make_float4(0.f, 0.f, 0.f, 0.f), f1 = f0;
            if (row < nc) {
                const float* src = msg_c + (size_t)row * HIDDEN + ks * 32 + quad * 8;
                f0 = *(const float4*)src;
                f1 = *(const float4*)(src + 4);
            }
            short8 ah, al;
            cvt8_split(f0, f1, ah, al);
            #pragma unroll
            for (int nt = 0; nt < 4; ++nt) {
                acc[nt] = __builtin_amdgcn_mfma_f32_16x16x32_bf16(ah, Wb[ks][nt], acc[nt], 0, 0, 0);
                acc[nt] = __builtin_amdgcn_mfma_f32_16x16x32_bf16(al, Wb[ks][nt], acc[nt], 0, 0, 0);
            }
        }
        float res[4];
        #pragma unroll
        for (int gg = 0; gg < 4; ++gg) {
            float part = 0.0f;
            #pragma unroll
            for (int nt = 0; nt < 4; ++nt)
                part += fmaxf(acc[nt][gg] + bias[nt], 0.0f) * wo[nt];
            part += __shfl_xor(part, 1);
            part += __shfl_xor(part, 2);
            part += __shfl_xor(part, 4);
            part += __shfl_xor(part, 8);
            res[gg] = part;
        }
        if (r == 0) {
            #pragma unroll
            for (int gg = 0; gg < 4; ++gg) {
                const int idx = i0 + quad * 4 + gg;
                if (idx < nc)
                    res_c[idx] = 1.0f / (1.0f + __expf(-(res[gg] + bo_s)));
            }
        }
    }
}

// Final map: out[p] = res_c[inv[post[p]]].
__global__ __launch_bounds__(256) void k_out(
    const int* __restrict__ post, const int* __restrict__ inv,
    const float* __restrict__ res_c, float* __restrict__ out, int n_posts)
{
    const int p = blockIdx.x * 256 + threadIdx.x;
    if (p < n_posts) out[p] = res_c[inv[post[p]]];
}

extern "C" void kernel_launch(void* const* d_in, const int* in_sizes, int n_in,
                              void* d_out, int out_size, void* d_ws, size_t ws_size,
                              hipStream_t stream) {
    BuildP P;
    P.A    = (const float*)d_in[0];
    const int* ei = (const int*)d_in[1];
    P.post = (const int*)d_in[2];
    P.We   = (const float*)d_in[3];
    P.be   = (const float*)d_in[4];
    const float* Wc = (const float*)d_in[5];
    const float* bc = (const float*)d_in[6];
    const float* Wo = (const float*)d_in[7];
    const float* bo = (const float*)d_in[8];
    float* out = (float*)d_out;

    P.n_nodes = in_sizes[0] / NODE_DIM;   // 100000
    P.n_edges = in_sizes[1] / 2;          // 1200000
    P.n_posts = in_sizes[2];              // 50000
    P.n_tiles = P.n_nodes / 16;
    P.srcs = ei;
    P.dsts = ei + P.n_edges;

    // ---- workspace layout (~33 MB; every region written before read) ----
    char* p = (char*)d_ws;
    P.emb16 = (__hip_bfloat16*)p;   p += (size_t)P.n_nodes * HIDDEN * 2;   // 12.8 MB
    float* msg_c = (float*)p;       p += (size_t)P.n_posts * HIDDEN * 4;   // 12.8 MB
    P.slots = (int*)p;              p += (size_t)P.n_edges * 4;            // 4.8 MB
    // zeroed ctrl region (contiguous): count | bits | listCnt | partials | bars
    char* zbase = p;
    P.count    = (int*)p;           p += (size_t)P.n_nodes * 4;
    P.bits     = (unsigned int*)p;  p += ((size_t)(P.n_nodes + 31) / 32 + 32) * 4;
    P.listCnt  = (int*)p;           p += 256;
    P.partials = (unsigned int*)p;  p += 1024;
    P.bars     = (int*)p;           p += 256;
    const size_t zbytes = (size_t)(p - zbase);
    P.row_start = (int*)p;          p += (size_t)P.n_nodes * 4;
    P.nodelist  = (int*)p;          p += (size_t)P.n_nodes * 4;
    P.inv       = (int*)p;          p += (size_t)P.n_nodes * 4;
    float* res_c = (float*)p;       p += (size_t)P.n_posts * 4;

    // Runtime occupancy-derived grid (host-only queries; graph-capture safe).
    int ncu = 256;
    hipDeviceGetAttribute(&ncu, hipDeviceAttributeMultiprocessorCount, 0);
    int occ = 0;
    if (hipOccupancyMaxActiveBlocksPerMultiprocessor(&occ, k_build, 256, 0) != hipSuccess || occ < 1)
        occ = 1;
    int grid = occ * ncu;
    if (grid > 512) grid = 512;
    int cblk = (grid * 3) / 8;
    if (cblk < 98) cblk = 98;             // scan needs >= 98 chunk blocks
    if (cblk > grid - 4) cblk = grid - 4; // keep some encode blocks
    P.cblk = cblk;
    P.eblk = grid - cblk;

    hipMemsetAsync(zbase, 0, zbytes, stream);
    k_build<<<grid, 256, 0, stream>>>(P);
    k_gather<<<8192, 256, 0, stream>>>(P.nodelist, P.listCnt, P.row_start, P.count,
                                       P.slots, P.emb16, msg_c);
    k_head_mfma<<<1024, 256, 0, stream>>>(P.listCnt, msg_c, Wc, bc, Wo, bo, res_c);
    k_out<<<(P.n_posts + 255) / 256, 256, 0, stream>>>(P.post, P.inv, res_c, out, P.n_posts);
}

// Round 11
// 221.966 us; speedup vs baseline: 1.0900x; 1.0900x over previous
//
#include <hip/hip_runtime.h>
#include <hip/hip_bf16.h>
#include <math.h>

// Problem shape (SimpleGCN):
//   node_features [N=100000, 128] f32
//   edge_index    [2, E=1200000] i32   (row 0 = src, row 1 = dst)
//   post_mask     [P=50000] i32
// out[p] = sigmoid( relu( (emb + segsum(emb[src]->dst))[post[p]] @ Wc + bc ) @ Wo + bo )
//
// Round-11: consolidate on the proven round-8 structure (fusions in R6/R9/R10
// all lost: intra-kernel partitioning starves width). Trims: 14 KB memset
// (count[] zeroed inside encode), no flag/inv arrays (bitmask dedup; head
// writes res[node] directly), 8 dispatches instead of 10.

#define HIDDEN 64
#define NODE_DIM 128
#define SCAN_CHUNK 1024

typedef __attribute__((ext_vector_type(8))) short short8;   // 8 bf16 (4 VGPR)
typedef __attribute__((ext_vector_type(4))) float floatx4;  // mfma C/D frag

union F2B { short8 s; __hip_bfloat162 h[4]; };

__device__ inline short8 cvt8(const float4& p, const float4& q) {
    F2B u;
    u.h[0] = __float22bfloat162_rn(make_float2(p.x, p.y));
    u.h[1] = __float22bfloat162_rn(make_float2(p.z, p.w));
    u.h[2] = __float22bfloat162_rn(make_float2(q.x, q.y));
    u.h[3] = __float22bfloat162_rn(make_float2(q.z, q.w));
    return u.s;
}

// hi/lo bf16 split of 8 floats: hi = bf16(x), lo = bf16(x - float(hi)).
__device__ inline void cvt8_split(const float4& p, const float4& q,
                                  short8& hi, short8& lo) {
    const float f[8] = {p.x, p.y, p.z, p.w, q.x, q.y, q.z, q.w};
    F2B uh, ul;
    #pragma unroll
    for (int jj = 0; jj < 4; ++jj) {
        const float2 v = make_float2(f[2 * jj], f[2 * jj + 1]);
        const __hip_bfloat162 h = __float22bfloat162_rn(v);
        const float2 hv = __bfloat1622float2(h);
        ul.h[jj] = __float22bfloat162_rn(make_float2(v.x - hv.x, v.y - hv.y));
        uh.h[jj] = h;
    }
    hi = uh.s; lo = ul.s;
}

// ---------------------------------------------------------------------------
// Setflags: bitmask dedup (atomicOr return) + compact nodelist append.
// bits/listCnt pre-zeroed by the 14 KB memset.
// ---------------------------------------------------------------------------
__global__ __launch_bounds__(256) void k_setflags(
    const int* __restrict__ post, unsigned int* __restrict__ bits,
    int* __restrict__ nodelist, int* __restrict__ listCnt, int n_posts)
{
    const int p = blockIdx.x * 256 + threadIdx.x;
    if (p >= n_posts) return;
    const int n = post[p];
    const unsigned int bit = 1u << (n & 31);
    const unsigned int old = atomicOr(&bits[n >> 5], bit);
    if (!(old & bit)) {
        const int i = atomicAdd(listCnt, 1);
        nodelist[i] = n;
    }
}

// ---------------------------------------------------------------------------
// Stage 1 (MFMA): emb16 = bf16(relu(A @ We + be)). Also zeros count[] (this
// kernel precedes k_count in stream order, so no barrier is needed).
// Wave = 16-node M-tile: 4 ksteps x 4 ntiles of 16x16x32 bf16 mfma.
// ---------------------------------------------------------------------------
__global__ __launch_bounds__(256) void k_encode_mfma(
    const float* __restrict__ A, const float* __restrict__ We,
    const float* __restrict__ be, __hip_bfloat16* __restrict__ emb16,
    int* __restrict__ count, int n_nodes, int n_tiles)
{
    // zero count[] (one element per thread; grid is 1563*256 = 400k >= 100k)
    const int gtid = blockIdx.x * 256 + threadIdx.x;
    if (gtid < n_nodes) count[gtid] = 0;

    const int lane = threadIdx.x & 63;
    const int r    = lane & 15;
    const int quad = lane >> 4;

    short8 Wb[4][4];   // [kstep][ntile], built once per wave
    #pragma unroll
    for (int ks = 0; ks < 4; ++ks)
        #pragma unroll
        for (int nt = 0; nt < 4; ++nt) {
            F2B u;
            #pragma unroll
            for (int jj = 0; jj < 4; ++jj) {
                const int k0 = ks * 32 + quad * 8 + 2 * jj;
                const float lo = We[(size_t)k0 * HIDDEN + nt * 16 + r];
                const float hi = We[(size_t)(k0 + 1) * HIDDEN + nt * 16 + r];
                u.h[jj] = __float22bfloat162_rn(make_float2(lo, hi));
            }
            Wb[ks][nt] = u.s;
        }
    float bias[4];
    #pragma unroll
    for (int nt = 0; nt < 4; ++nt) bias[nt] = be[nt * 16 + r];

    const int wid    = (blockIdx.x * 256 + threadIdx.x) >> 6;
    const int nwaves = gridDim.x * 4;
    for (int t = wid; t < n_tiles; t += nwaves) {
        const float* Arow = A + (size_t)t * 16 * NODE_DIM + (size_t)r * NODE_DIM + quad * 8;
        float4 a[4][2];
        #pragma unroll
        for (int ks = 0; ks < 4; ++ks) {
            a[ks][0] = *(const float4*)(Arow + ks * 32);
            a[ks][1] = *(const float4*)(Arow + ks * 32 + 4);
        }
        floatx4 acc[4] = {};
        #pragma unroll
        for (int ks = 0; ks < 4; ++ks) {
            const short8 af = cvt8(a[ks][0], a[ks][1]);
            #pragma unroll
            for (int nt = 0; nt < 4; ++nt)
                acc[nt] = __builtin_amdgcn_mfma_f32_16x16x32_bf16(af, Wb[ks][nt], acc[nt], 0, 0, 0);
        }
        #pragma unroll
        for (int nt = 0; nt < 4; ++nt)
            #pragma unroll
            for (int g = 0; g < 4; ++g) {
                const int node = t * 16 + quad * 4 + g;
                const float h = fmaxf(acc[nt][g] + bias[nt], 0.0f);
                emb16[(size_t)node * HIDDEN + nt * 16 + r] = __float2bfloat16(h);
            }
    }
    // tail nodes (n_nodes % 16) — 0 for this shape
    const int rem = n_nodes - n_tiles * 16;
    if (rem > 0 && wid == 0) {
        for (int n = n_tiles * 16; n < n_nodes; ++n) {
            float acc = be[lane];
            const float* row = A + (size_t)n * NODE_DIM;
            for (int k = 0; k < NODE_DIM; ++k)
                acc = fmaf(row[k], We[(size_t)k * HIDDEN + lane], acc);
            emb16[(size_t)n * HIDDEN + lane] = __float2bfloat16(fmaxf(acc, 0.0f));
        }
    }
}

// CSR step 1: in-degree count per flagged destination (bitmask check = L1 hit).
__global__ __launch_bounds__(256) void k_count(
    const int* __restrict__ dsts, const unsigned int* __restrict__ bits,
    int* __restrict__ count, int n_edges)
{
    const int stride = gridDim.x * 256;
    for (int e = blockIdx.x * 256 + threadIdx.x; e < n_edges; e += stride) {
        const int d = dsts[e];
        if ((bits[d >> 5] >> (d & 31)) & 1u) atomicAdd(&count[d], 1);
    }
}

// ---------------------------------------------------------------------------
// CSR step 2: single-pass exclusive scan (decoupled lookback).
// ---------------------------------------------------------------------------
__global__ __launch_bounds__(256) void k_scan_lb(
    const int* __restrict__ count, int* __restrict__ row_start,
    unsigned int* __restrict__ partials, int n)
{
    __shared__ int s[256];
    __shared__ int sExc;
    const int b = blockIdx.x, tid = threadIdx.x;
    const int base = b * SCAN_CHUNK + tid * 4;
    int c0 = (base + 0 < n) ? count[base + 0] : 0;
    int c1 = (base + 1 < n) ? count[base + 1] : 0;
    int c2 = (base + 2 < n) ? count[base + 2] : 0;
    int c3 = (base + 3 < n) ? count[base + 3] : 0;
    const int t = c0 + c1 + c2 + c3;
    s[tid] = t;
    __syncthreads();
    #pragma unroll
    for (int off = 1; off < 256; off <<= 1) {
        int v = (tid >= off) ? s[tid - off] : 0;
        __syncthreads();
        s[tid] += v;
        __syncthreads();
    }
    if (tid == 0) {
        const unsigned int total = (unsigned int)s[255];
        if (b == 0) {
            __hip_atomic_store(&partials[0], (2u << 30) | total,
                               __ATOMIC_RELEASE, __HIP_MEMORY_SCOPE_AGENT);
            sExc = 0;
        } else {
            __hip_atomic_store(&partials[b], (1u << 30) | total,
                               __ATOMIC_RELEASE, __HIP_MEMORY_SCOPE_AGENT);
            int exc = 0, j = b - 1;
            while (true) {
                const unsigned int v = __hip_atomic_load(&partials[j],
                    __ATOMIC_ACQUIRE, __HIP_MEMORY_SCOPE_AGENT);
                const unsigned int st = v >> 30;
                if (st == 0u) { __builtin_amdgcn_s_sleep(1); continue; }
                exc += (int)(v & 0x3FFFFFFFu);
                if (st == 2u) break;
                --j;
            }
            __hip_atomic_store(&partials[b], (2u << 30) | (unsigned int)(exc + (int)total),
                               __ATOMIC_RELEASE, __HIP_MEMORY_SCOPE_AGENT);
            sExc = exc;
        }
    }
    __syncthreads();
    int run = sExc + s[tid] - t;
    if (base + 0 < n) row_start[base + 0] = run;           run += c0;
    if (base + 1 < n) row_start[base + 1] = run;           run += c1;
    if (base + 2 < n) row_start[base + 2] = run;           run += c2;
    if (base + 3 < n) row_start[base + 3] = run;
}

// CSR step 3: fill slot lists; atomically consumes row_start -> row_end.
__global__ __launch_bounds__(256) void k_fill(
    const int* __restrict__ srcs, const int* __restrict__ dsts,
    const unsigned int* __restrict__ bits, int* __restrict__ row_start,
    int* __restrict__ slots, int n_edges)
{
    const int stride = gridDim.x * 256;
    for (int e = blockIdx.x * 256 + threadIdx.x; e < n_edges; e += stride) {
        const int d = dsts[e];
        if (!((bits[d >> 5] >> (d & 31)) & 1u)) continue;
        const int idx = atomicAdd(&row_start[d], 1);
        slots[idx] = srcs[e];
    }
}

// ---------------------------------------------------------------------------
// Gather (proven round-8): one wave per compact node. 8 groups x 8 lanes;
// one 128 B bf16 row per group; 2-deep unroll -> 16 rows in flight.
// ---------------------------------------------------------------------------
__global__ __launch_bounds__(256) void k_gather(
    const int* __restrict__ nodelist, const int* __restrict__ listCnt,
    const int* __restrict__ row_end, const int* __restrict__ count,
    const int* __restrict__ slots, const __hip_bfloat16* __restrict__ emb16,
    float* __restrict__ msg_c)
{
    const int lane = threadIdx.x & 63;
    const int j    = lane & 7;
    const int g    = lane >> 3;
    const int gw   = (blockIdx.x * 256 + threadIdx.x) >> 6;
    const int nw   = gridDim.x * 4;
    const int nc   = listCnt[0];

    for (int i = gw; i < nc; i += nw) {
        const int n    = nodelist[i];
        const int m    = count[n];
        const int base = row_end[n] - m;

        float2 a0 = {0.f, 0.f}, a1 = {0.f, 0.f}, a2 = {0.f, 0.f}, a3 = {0.f, 0.f};
        #define ACC8(v)  do { F2B u; u.s = (v); float2 t;                       \
            t = __bfloat1622float2(u.h[0]); a0.x += t.x; a0.y += t.y;           \
            t = __bfloat1622float2(u.h[1]); a1.x += t.x; a1.y += t.y;           \
            t = __bfloat1622float2(u.h[2]); a2.x += t.x; a2.y += t.y;           \
            t = __bfloat1622float2(u.h[3]); a3.x += t.x; a3.y += t.y; } while (0)

        if (g == 0) {
            const short8 v = *(const short8*)(emb16 + (size_t)n * HIDDEN + j * 8);
            ACC8(v);
        }
        int c = g;
        for (; c + 8 < m; c += 16) {
            const int s0 = slots[base + c];
            const int s1 = slots[base + c + 8];
            const short8 v0 = *(const short8*)(emb16 + (size_t)s0 * HIDDEN + j * 8);
            const short8 v1 = *(const short8*)(emb16 + (size_t)s1 * HIDDEN + j * 8);
            ACC8(v0); ACC8(v1);
        }
        for (; c < m; c += 8) {
            const int s0 = slots[base + c];
            const short8 v0 = *(const short8*)(emb16 + (size_t)s0 * HIDDEN + j * 8);
            ACC8(v0);
        }
        #undef ACC8

        #pragma unroll
        for (int off = 8; off < 64; off <<= 1) {
            a0.x += __shfl_xor(a0.x, off); a0.y += __shfl_xor(a0.y, off);
            a1.x += __shfl_xor(a1.x, off); a1.y += __shfl_xor(a1.y, off);
            a2.x += __shfl_xor(a2.x, off); a2.y += __shfl_xor(a2.y, off);
            a3.x += __shfl_xor(a3.x, off); a3.y += __shfl_xor(a3.y, off);
        }
        if (g == 0) {
            float4* dst = (float4*)(msg_c + (size_t)i * HIDDEN + j * 8);
            dst[0] = make_float4(a0.x, a0.y, a1.x, a1.y);
            dst[1] = make_float4(a2.x, a2.y, a3.x, a3.y);
        }
    }
}

// ---------------------------------------------------------------------------
// Head (MFMA): wave per 16 compact rows of msg_c; writes res[node] directly
// (node = nodelist[idx]) so the final map needs only one random read.
// ---------------------------------------------------------------------------
__global__ __launch_bounds__(256) void k_head_mfma(
    const int* __restrict__ listCnt, const int* __restrict__ nodelist,
    const float* __restrict__ msg_c,
    const float* __restrict__ Wc, const float* __restrict__ bc,
    const float* __restrict__ Wo, const float* __restrict__ bo,
    float* __restrict__ res)
{
    const int lane = threadIdx.x & 63;
    const int r    = lane & 15;
    const int quad = lane >> 4;

    short8 Wb[2][4];
    #pragma unroll
    for (int ks = 0; ks < 2; ++ks)
        #pragma unroll
        for (int nt = 0; nt < 4; ++nt) {
            F2B u;
            #pragma unroll
            for (int jj = 0; jj < 4; ++jj) {
                const int k0 = ks * 32 + quad * 8 + 2 * jj;
                const float lo = Wc[(size_t)k0 * HIDDEN + nt * 16 + r];
                const float hi = Wc[(size_t)(k0 + 1) * HIDDEN + nt * 16 + r];
                u.h[jj] = __float22bfloat162_rn(make_float2(lo, hi));
            }
            Wb[ks][nt] = u.s;
        }
    float bias[4], wo[4];
    #pragma unroll
    for (int nt = 0; nt < 4; ++nt) { bias[nt] = bc[nt * 16 + r]; wo[nt] = Wo[nt * 16 + r]; }
    const float bo_s = bo[0];

    const int nc      = listCnt[0];
    const int n_tiles = (nc + 15) / 16;
    const int wid     = (blockIdx.x * 256 + threadIdx.x) >> 6;
    const int nwaves  = gridDim.x * 4;

    for (int tile = wid; tile < n_tiles; tile += nwaves) {
        const int i0  = tile * 16;
        const int row = i0 + r;
        floatx4 acc[4] = {};
        #pragma unroll
        for (int ks = 0; ks < 2; ++ks) {
            float4 f0 = make_float4(0.f, 0.f, 0.f, 0.f), f1 = f0;
            if (row < nc) {
                const float* src = msg_c + (size_t)row * HIDDEN + ks * 32 + quad * 8;
                f0 = *(const float4*)src;
                f1 = *(const float4*)(src + 4);
            }
            short8 ah, al;
            cvt8_split(f0, f1, ah, al);
            #pragma unroll
            for (int nt = 0; nt < 4; ++nt) {
                acc[nt] = __builtin_amdgcn_mfma_f32_16x16x32_bf16(ah, Wb[ks][nt], acc[nt], 0, 0, 0);
                acc[nt] = __builtin_amdgcn_mfma_f32_16x16x32_bf16(al, Wb[ks][nt], acc[nt], 0, 0, 0);
            }
        }
        float r4[4];
        #pragma unroll
        for (int gg = 0; gg < 4; ++gg) {
            float part = 0.0f;
            #pragma unroll
            for (int nt = 0; nt < 4; ++nt)
                part += fmaxf(acc[nt][gg] + bias[nt], 0.0f) * wo[nt];
            part += __shfl_xor(part, 1);
            part += __shfl_xor(part, 2);
            part += __shfl_xor(part, 4);
            part += __shfl_xor(part, 8);
            r4[gg] = part;
        }
        if (r == 0) {
            #pragma unroll
            for (int gg = 0; gg < 4; ++gg) {
                const int idx = i0 + quad * 4 + gg;
                if (idx < nc)
                    res[nodelist[idx]] = 1.0f / (1.0f + __expf(-(r4[gg] + bo_s)));
            }
        }
    }
}

// Final map: out[p] = res[post[p]] (single random L2 read).
__global__ __launch_bounds__(256) void k_out(
    const int* __restrict__ post, const float* __restrict__ res,
    float* __restrict__ out, int n_posts)
{
    const int p = blockIdx.x * 256 + threadIdx.x;
    if (p < n_posts) out[p] = res[post[p]];
}

extern "C" void kernel_launch(void* const* d_in, const int* in_sizes, int n_in,
                              void* d_out, int out_size, void* d_ws, size_t ws_size,
                              hipStream_t stream) {
    const float* A    = (const float*)d_in[0];
    const int*   ei   = (const int*)  d_in[1];
    const int*   post = (const int*)  d_in[2];
    const float* We   = (const float*)d_in[3];
    const float* be   = (const float*)d_in[4];
    const float* Wc   = (const float*)d_in[5];
    const float* bc   = (const float*)d_in[6];
    const float* Wo   = (const float*)d_in[7];
    const float* bo   = (const float*)d_in[8];
    float* out = (float*)d_out;

    const int n_nodes = in_sizes[0] / NODE_DIM;   // 100000
    const int n_edges = in_sizes[1] / 2;          // 1200000
    const int n_posts = in_sizes[2];              // 50000

    // ---- workspace layout (~33 MB; every region written before read) ----
    char* p = (char*)d_ws;
    __hip_bfloat16* emb16 = (__hip_bfloat16*)p;  p += (size_t)n_nodes * HIDDEN * 2;  // 12.8 MB
    float* msg_c    = (float*)p;              p += (size_t)n_posts * HIDDEN * 4;     // 12.8 MB
    int*   slots    = (int*)p;                p += (size_t)n_edges * 4;              // 4.8 MB
    // small ctrl region zeroed by memset: bits | listCnt | partials
    char* zbase = p;
    unsigned int* bits = (unsigned int*)p;    p += ((size_t)(n_nodes + 31) / 32 + 32) * 4;
    int*   listCnt  = (int*)p;                p += 256;
    unsigned int* partials = (unsigned int*)p; p += 1024;
    const size_t zbytes = (size_t)(p - zbase);                                       // ~14 KB
    int*   count    = (int*)p;                p += (size_t)n_nodes * 4;   // zeroed in k_encode
    int*   row_start= (int*)p;                p += (size_t)n_nodes * 4;
    int*   nodelist = (int*)p;                p += (size_t)n_nodes * 4;
    float* res      = (float*)p;              p += (size_t)n_nodes * 4;

    const int* srcs = ei;
    const int* dsts = ei + n_edges;
    const int nb = (n_nodes + SCAN_CHUNK - 1) / SCAN_CHUNK;   // 98
    const int n_tiles = n_nodes / 16;

    hipMemsetAsync(zbase, 0, zbytes, stream);
    k_setflags<<<(n_posts + 255) / 256, 256, 0, stream>>>(post, bits, nodelist, listCnt, n_posts);
    k_encode_mfma<<<(n_tiles + 3) / 4, 256, 0, stream>>>(A, We, be, emb16, count, n_nodes, n_tiles);
    k_count<<<2048, 256, 0, stream>>>(dsts, bits, count, n_edges);
    k_scan_lb<<<nb, 256, 0, stream>>>(count, row_start, partials, n_nodes);
    k_fill<<<2048, 256, 0, stream>>>(srcs, dsts, bits, row_start, slots, n_edges);
    k_gather<<<8192, 256, 0, stream>>>(nodelist, listCnt, row_start, count, slots, emb16, msg_c);
    k_head_mfma<<<1024, 256, 0, stream>>>(listCnt, nodelist, msg_c, Wc, bc, Wo, bo, res);
    k_out<<<(n_posts + 255) / 256, 256, 0, stream>>>(post, res, out, n_posts);
}